// Round 1
// baseline (778.118 us; speedup 1.0000x reference)
//
#include <hip/hip_runtime.h>

#define D 128
#define LRELU(x) ((x) > 0.f ? (x) : 0.2f * (x))

// ---------------- edge-index width detection ----------------
// Reference dtype is int64; harness doc says int32. Detect on device:
// if data is int64, every odd 32-bit word (high half) is 0 since 0<=idx<2^31.
__global__ void detect_i64(const unsigned int* ei, int* flag) {
    if (threadIdx.x == 0 && blockIdx.x == 0) {
        unsigned int o = 0;
#pragma unroll
        for (int k = 0; k < 64; ++k) o |= ei[2 * k + 1];
        *flag = (o == 0u) ? 1 : 0;
    }
}

__device__ __forceinline__ int load_idx(const void* ei, long long pos, int is64) {
    if (is64) return (int)((const long long*)ei)[pos];
    return ((const int*)ei)[pos];
}

// ---------------- CSR construction ----------------
__global__ void hist_kernel(const void* __restrict__ ei, const int* __restrict__ flag,
                            int* __restrict__ count, int E) {
    int e = blockIdx.x * blockDim.x + threadIdx.x;
    if (e >= E) return;
    int is64 = *flag;
    int dst = load_idx(ei, (long long)E + e, is64);
    atomicAdd(&count[dst], 1);
}

__global__ void reduce_1024(const int* __restrict__ count, int* __restrict__ bsum, int n) {
    __shared__ int sm[256];
    int t = threadIdx.x, b = blockIdx.x;
    int base = b * 1024 + t * 4;
    int s = 0;
#pragma unroll
    for (int j = 0; j < 4; ++j)
        if (base + j < n) s += count[base + j];
    sm[t] = s;
    __syncthreads();
    for (int of = 128; of >= 1; of >>= 1) {
        if (t < of) sm[t] += sm[t + of];
        __syncthreads();
    }
    if (t == 0) bsum[b] = sm[0];
}

__global__ void scan_partials(int* __restrict__ bsum_ex, const int* __restrict__ bsum, int B) {
    __shared__ int sm[256];
    int t = threadIdx.x;
    int v = (t < B) ? bsum[t] : 0;
    sm[t] = v;
    __syncthreads();
    for (int of = 1; of < 256; of <<= 1) {
        int u = (t >= of) ? sm[t - of] : 0;
        __syncthreads();
        sm[t] += u;
        __syncthreads();
    }
    if (t < B) bsum_ex[t] = sm[t] - v;
}

__global__ void scan_final(const int* __restrict__ count, const int* __restrict__ bsum_ex,
                           int* __restrict__ offsets, int n) {
    __shared__ int sm[256];
    int t = threadIdx.x, b = blockIdx.x;
    int base = b * 1024 + t * 4;
    int c[4];
#pragma unroll
    for (int j = 0; j < 4; ++j) c[j] = (base + j < n) ? count[base + j] : 0;
    int tsum = c[0] + c[1] + c[2] + c[3];
    sm[t] = tsum;
    __syncthreads();
    for (int of = 1; of < 256; of <<= 1) {
        int u = (t >= of) ? sm[t - of] : 0;
        __syncthreads();
        sm[t] += u;
        __syncthreads();
    }
    int o = bsum_ex[b] + sm[t] - tsum;  // exclusive prefix for this thread
#pragma unroll
    for (int j = 0; j < 4; ++j) {
        if (base + j < n) offsets[base + j] = o;
        o += c[j];
    }
}

__global__ void scatter_kernel(const void* __restrict__ ei, const int* __restrict__ flag,
                               const int* __restrict__ offsets, int* __restrict__ cursor,
                               int* __restrict__ col, int E) {
    int e = blockIdx.x * blockDim.x + threadIdx.x;
    if (e >= E) return;
    int is64 = *flag;
    int src = load_idx(ei, e, is64);
    int dst = load_idx(ei, (long long)E + e, is64);
    int pos = offsets[dst] + atomicAdd(&cursor[dst], 1);
    col[pos] = src;
}

// ---------------- f32 GEMM: Y[N,128] = X[N,128] @ W[128,128] ----------------
// 64-row tile, K split in two 64-phases. Xt transposed in LDS (conflict-free
// float4 reads: lanes span 64 consecutive r-words -> 2/bank). W micro-cols are
// {cb..cb+3} U {cb+64..cb+67} so each b128 read spans words 0..63 (2/bank).
__launch_bounds__(256, 2)
__global__ void gemm_nn_128(const float* __restrict__ X, const float* __restrict__ W,
                            float* __restrict__ Y, int n) {
    __shared__ float Xt[64][68];   // [k][r], padded row
    __shared__ float Wl[64][128];  // [k][c]
    const int t = threadIdx.x;
    const int r0 = blockIdx.x * 64;
    const int rb = (t >> 4) * 4;
    const int cb = (t & 15) * 4;
    float acc[4][8] = {};
    for (int ph = 0; ph < 2; ++ph) {
        // stage X^T (64 rows x 64 k)
#pragma unroll
        for (int it = 0; it < 4; ++it) {
            int idx = t + it * 256;
            int r = idx >> 4, kq = idx & 15;
            float4 xv = make_float4(0.f, 0.f, 0.f, 0.f);
            if (r0 + r < n)
                xv = *reinterpret_cast<const float4*>(X + (size_t)(r0 + r) * D + ph * 64 + kq * 4);
            Xt[kq * 4 + 0][r] = xv.x;
            Xt[kq * 4 + 1][r] = xv.y;
            Xt[kq * 4 + 2][r] = xv.z;
            Xt[kq * 4 + 3][r] = xv.w;
        }
        // stage W (64 k x 128 c)
#pragma unroll
        for (int it = 0; it < 8; ++it) {
            int idx = t + it * 256;
            int k = idx >> 5, c4 = idx & 31;
            *reinterpret_cast<float4*>(&Wl[k][c4 * 4]) =
                *reinterpret_cast<const float4*>(W + (size_t)(ph * 64 + k) * D + c4 * 4);
        }
        __syncthreads();
#pragma unroll 4
        for (int k = 0; k < 64; ++k) {
            float4 a = *reinterpret_cast<const float4*>(&Xt[k][rb]);
            float4 b0 = *reinterpret_cast<const float4*>(&Wl[k][cb]);
            float4 b1 = *reinterpret_cast<const float4*>(&Wl[k][cb + 64]);
            float av[4] = {a.x, a.y, a.z, a.w};
            float bv[8] = {b0.x, b0.y, b0.z, b0.w, b1.x, b1.y, b1.z, b1.w};
#pragma unroll
            for (int i = 0; i < 4; ++i)
#pragma unroll
                for (int j = 0; j < 8; ++j) acc[i][j] = fmaf(av[i], bv[j], acc[i][j]);
        }
        __syncthreads();
    }
#pragma unroll
    for (int i = 0; i < 4; ++i) {
        int row = r0 + rb + i;
        if (row < n) {
            float4 o0 = make_float4(acc[i][0], acc[i][1], acc[i][2], acc[i][3]);
            float4 o1 = make_float4(acc[i][4], acc[i][5], acc[i][6], acc[i][7]);
            *reinterpret_cast<float4*>(Y + (size_t)row * D + cb) = o0;
            *reinterpret_cast<float4*>(Y + (size_t)row * D + cb + 64) = o1;
        }
    }
}

// ---------------- attention score vectors: s[n][h] = sum_c xp[n,h*C+c]*a[h*C+c] ----------------
// one wave per node; lane owns channels (lane, lane+64).
template <int H>
__launch_bounds__(256)
__global__ void score_kernel(const float* __restrict__ xp, const float* __restrict__ a_src,
                             const float* __restrict__ a_dst, float* __restrict__ s_src,
                             float* __restrict__ s_dst, int n) {
    int wid = (blockIdx.x * 256 + threadIdx.x) >> 6;
    int lane = threadIdx.x & 63;
    if (wid >= n) return;
    const float* row = xp + (size_t)wid * D;
    float x0 = row[lane], x1 = row[lane + 64];
    float ps0 = x0 * a_src[lane], ps1 = x1 * a_src[lane + 64];
    float pd0 = x0 * a_dst[lane], pd1 = x1 * a_dst[lane + 64];
    if (H == 4) {
        // reduce within the two 32-lane halves: lanes 0-31 hold heads {0,2}, 32-63 hold {1,3}
        for (int m = 16; m >= 1; m >>= 1) {
            ps0 += __shfl_xor(ps0, m);
            ps1 += __shfl_xor(ps1, m);
            pd0 += __shfl_xor(pd0, m);
            pd1 += __shfl_xor(pd1, m);
        }
        if (lane == 0) {
            s_src[wid * 4 + 0] = ps0; s_src[wid * 4 + 2] = ps1;
            s_dst[wid * 4 + 0] = pd0; s_dst[wid * 4 + 2] = pd1;
        }
        if (lane == 32) {
            s_src[wid * 4 + 1] = ps0; s_src[wid * 4 + 3] = ps1;
            s_dst[wid * 4 + 1] = pd0; s_dst[wid * 4 + 3] = pd1;
        }
    } else {
        float ps = ps0 + ps1, pd = pd0 + pd1;
        for (int m = 32; m >= 1; m >>= 1) {
            ps += __shfl_xor(ps, m);
            pd += __shfl_xor(pd, m);
        }
        if (lane == 0) { s_src[wid] = ps; s_dst[wid] = pd; }
    }
}

// ---------------- segment softmax stats (max + sum), wave per node ----------------
template <int H>
__launch_bounds__(256)
__global__ void softmax_stats(const int* __restrict__ col, const int* __restrict__ offsets,
                              const int* __restrict__ deg_arr, const float* __restrict__ s_src,
                              const float* __restrict__ s_dst, float* __restrict__ m_out,
                              float* __restrict__ rd_out, int n) {
    int wid = (blockIdx.x * 256 + threadIdx.x) >> 6;
    int lane = threadIdx.x & 63;
    if (wid >= n) return;
    int off = offsets[wid];
    int deg = deg_arr[wid];
    float sd[H], mx[H], eself[H];
#pragma unroll
    for (int h = 0; h < H; ++h) {
        sd[h] = s_dst[wid * H + h];
        float e = s_src[wid * H + h] + sd[h];
        eself[h] = LRELU(e);
        mx[h] = eself[h];
    }
    for (int i = lane; i < deg; i += 64) {
        int s = col[off + i];
        if (H == 4) {
            float4 ss = *reinterpret_cast<const float4*>(s_src + (size_t)s * 4);
            float e0 = LRELU(ss.x + sd[0]); mx[0] = fmaxf(mx[0], e0);
            float e1 = LRELU(ss.y + sd[1]); mx[1] = fmaxf(mx[1], e1);
            float e2 = LRELU(ss.z + sd[2]); mx[2] = fmaxf(mx[2], e2);
            float e3 = LRELU(ss.w + sd[3]); mx[3] = fmaxf(mx[3], e3);
        } else {
            float e = LRELU(s_src[s] + sd[0]);
            mx[0] = fmaxf(mx[0], e);
        }
    }
#pragma unroll
    for (int h = 0; h < H; ++h)
        for (int m = 32; m >= 1; m >>= 1) mx[h] = fmaxf(mx[h], __shfl_xor(mx[h], m));
    float sum[H];
#pragma unroll
    for (int h = 0; h < H; ++h) sum[h] = 0.f;
    for (int i = lane; i < deg; i += 64) {
        int s = col[off + i];
        if (H == 4) {
            float4 ss = *reinterpret_cast<const float4*>(s_src + (size_t)s * 4);
            sum[0] += __expf(LRELU(ss.x + sd[0]) - mx[0]);
            sum[1] += __expf(LRELU(ss.y + sd[1]) - mx[1]);
            sum[2] += __expf(LRELU(ss.z + sd[2]) - mx[2]);
            sum[3] += __expf(LRELU(ss.w + sd[3]) - mx[3]);
        } else {
            sum[0] += __expf(LRELU(s_src[s] + sd[0]) - mx[0]);
        }
    }
#pragma unroll
    for (int h = 0; h < H; ++h)
        for (int m = 32; m >= 1; m >>= 1) sum[h] += __shfl_xor(sum[h], m);
    if (lane == 0) {
#pragma unroll
        for (int h = 0; h < H; ++h) {
            float tot = sum[h] + __expf(eself[h] - mx[h]);  // self-loop term
            m_out[wid * H + h] = mx[h];
            rd_out[wid * H + h] = 1.f / (tot + 1e-16f);
        }
    }
}

// ---------------- weighted aggregation, wave per node, lanes own channels ----------------
template <int H, bool DO_ELU>
__launch_bounds__(256)
__global__ void aggregate(const int* __restrict__ col, const int* __restrict__ offsets,
                          const int* __restrict__ deg_arr, const float* __restrict__ xp,
                          const float* __restrict__ s_src, const float* __restrict__ s_dst,
                          const float* __restrict__ m_in, const float* __restrict__ rd_in,
                          const float* __restrict__ bias, float* __restrict__ out, int n) {
    int wid = (blockIdx.x * 256 + threadIdx.x) >> 6;
    int lane = threadIdx.x & 63;
    if (wid >= n) return;
    int off = offsets[wid], deg = deg_arr[wid];
    int h0 = (H == 4) ? (lane >> 5) : 0;
    int h1 = (H == 4) ? 2 + (lane >> 5) : 0;
    float sd0 = s_dst[wid * H + h0], sd1 = s_dst[wid * H + h1];
    float m0 = m_in[wid * H + h0], m1 = m_in[wid * H + h1];
    float rd0 = rd_in[wid * H + h0], rd1 = rd_in[wid * H + h1];
    float acc0, acc1;
    {   // self loop
        float ss0 = s_src[wid * H + h0], ss1 = s_src[wid * H + h1];
        float p0 = __expf(LRELU(ss0 + sd0) - m0) * rd0;
        float p1 = __expf(LRELU(ss1 + sd1) - m1) * rd1;
        const float* xr = xp + (size_t)wid * D;
        acc0 = p0 * xr[lane];
        acc1 = p1 * xr[lane + 64];
    }
    int s_next = (deg > 0) ? col[off] : 0;
    for (int i = 0; i < deg; ++i) {
        int s = s_next;
        if (i + 1 < deg) s_next = col[off + i + 1];
        float ss0 = s_src[(size_t)s * H + h0], ss1 = s_src[(size_t)s * H + h1];
        float p0 = __expf(LRELU(ss0 + sd0) - m0) * rd0;
        float p1 = __expf(LRELU(ss1 + sd1) - m1) * rd1;
        const float* xr = xp + (size_t)s * D;
        acc0 = fmaf(p0, xr[lane], acc0);
        acc1 = fmaf(p1, xr[lane + 64], acc1);
    }
    float v0 = acc0 + bias[lane];
    float v1 = acc1 + bias[lane + 64];
    if (DO_ELU) {
        v0 = v0 > 0.f ? v0 : expm1f(v0);
        v1 = v1 > 0.f ? v1 : expm1f(v1);
    }
    out[(size_t)wid * D + lane] = v0;
    out[(size_t)wid * D + lane + 64] = v1;
}

// ---------------- launch ----------------
extern "C" void kernel_launch(void* const* d_in, const int* in_sizes, int n_in,
                              void* d_out, int out_size, void* d_ws, size_t ws_size,
                              hipStream_t stream) {
    (void)n_in; (void)out_size; (void)ws_size;
    const float* x   = (const float*)d_in[0];
    const void*  ei  = d_in[1];
    const float* W1  = (const float*)d_in[2];
    const float* a1s = (const float*)d_in[3];
    const float* a1d = (const float*)d_in[4];
    const float* b1  = (const float*)d_in[5];
    const float* W2  = (const float*)d_in[6];
    const float* a2s = (const float*)d_in[7];
    const float* a2d = (const float*)d_in[8];
    const float* b2  = (const float*)d_in[9];
    const int N = in_sizes[0] / D;  // 100000
    const int E = in_sizes[1] / 2;  // 1600000
    float* out = (float*)d_out;

    char* p = (char*)d_ws;
    auto alloc = [&](size_t bytes) {
        char* q = p;
        p += (bytes + 255) & ~(size_t)255;
        return q;
    };
    float* xp      = (float*)alloc((size_t)N * D * 4);
    float* ssrc    = (float*)alloc((size_t)N * 4 * 4);
    float* sdst    = (float*)alloc((size_t)N * 4 * 4);
    float* mbuf    = (float*)alloc((size_t)N * 4 * 4);
    float* rdbuf   = (float*)alloc((size_t)N * 4 * 4);
    int*   count   = (int*)alloc((size_t)N * 4);
    int*   cursor  = (int*)alloc((size_t)N * 4);
    int*   offsets = (int*)alloc((size_t)N * 4);
    int*   bsum    = (int*)alloc(256 * 4);
    int*   bsumex  = (int*)alloc(256 * 4);
    int*   flag    = (int*)alloc(256);
    int*   col     = (int*)alloc((size_t)E * 4);

    hipMemsetAsync(count, 0, (size_t)N * 4, stream);
    hipMemsetAsync(cursor, 0, (size_t)N * 4, stream);

    detect_i64<<<1, 64, 0, stream>>>((const unsigned int*)ei, flag);
    int eg = (E + 255) / 256;
    hist_kernel<<<eg, 256, 0, stream>>>(ei, flag, count, E);
    int B = (N + 1023) / 1024;
    reduce_1024<<<B, 256, 0, stream>>>(count, bsum, N);
    scan_partials<<<1, 256, 0, stream>>>(bsumex, bsum, B);
    scan_final<<<B, 256, 0, stream>>>(count, bsumex, offsets, N);
    scatter_kernel<<<eg, 256, 0, stream>>>(ei, flag, offsets, cursor, col, E);

    int gemmG = (N + 63) / 64;
    int nodeG = (N + 3) / 4;

    // ----- layer 1 (H=4, ELU) -----
    gemm_nn_128<<<gemmG, 256, 0, stream>>>(x, W1, xp, N);
    score_kernel<4><<<nodeG, 256, 0, stream>>>(xp, a1s, a1d, ssrc, sdst, N);
    softmax_stats<4><<<nodeG, 256, 0, stream>>>(col, offsets, count, ssrc, sdst, mbuf, rdbuf, N);
    aggregate<4, true><<<nodeG, 256, 0, stream>>>(col, offsets, count, xp, ssrc, sdst, mbuf, rdbuf, b1, out, N);

    // ----- layer 2 (H=1, no activation); input = out (layer-1 h), safe: read before final write -----
    gemm_nn_128<<<gemmG, 256, 0, stream>>>(out, W2, xp, N);
    score_kernel<1><<<nodeG, 256, 0, stream>>>(xp, a2s, a2d, ssrc, sdst, N);
    softmax_stats<1><<<nodeG, 256, 0, stream>>>(col, offsets, count, ssrc, sdst, mbuf, rdbuf, N);
    aggregate<1, false><<<nodeG, 256, 0, stream>>>(col, offsets, count, xp, ssrc, sdst, mbuf, rdbuf, b2, out, N);
}

// Round 5
// 721.742 us; speedup vs baseline: 1.0781x; 1.0781x over previous
//
#include <hip/hip_runtime.h>

#define D 128
#define LRELU(x) ((x) > 0.f ? (x) : 0.2f * (x))

// ---------------- edge-index width detection ----------------
__global__ void detect_i64(const unsigned int* ei, int* flag) {
    if (threadIdx.x == 0 && blockIdx.x == 0) {
        unsigned int o = 0;
#pragma unroll
        for (int k = 0; k < 64; ++k) o |= ei[2 * k + 1];
        *flag = (o == 0u) ? 1 : 0;
    }
}

__device__ __forceinline__ int load_idx(const void* ei, long long pos, int is64) {
    if (is64) return (int)((const long long*)ei)[pos];
    return ((const int*)ei)[pos];
}

// ---------------- CSR construction ----------------
__global__ void hist_kernel(const void* __restrict__ ei, const int* __restrict__ flag,
                            int* __restrict__ count, int E) {
    int e = blockIdx.x * blockDim.x + threadIdx.x;
    if (e >= E) return;
    int is64 = *flag;
    int dst = load_idx(ei, (long long)E + e, is64);
    atomicAdd(&count[dst], 1);
}

__global__ void reduce_1024(const int* __restrict__ count, int* __restrict__ bsum, int n) {
    __shared__ int sm[256];
    int t = threadIdx.x, b = blockIdx.x;
    int base = b * 1024 + t * 4;
    int s = 0;
#pragma unroll
    for (int j = 0; j < 4; ++j)
        if (base + j < n) s += count[base + j];
    sm[t] = s;
    __syncthreads();
    for (int of = 128; of >= 1; of >>= 1) {
        if (t < of) sm[t] += sm[t + of];
        __syncthreads();
    }
    if (t == 0) bsum[b] = sm[0];
}

__global__ void scan_partials(int* __restrict__ bsum_ex, const int* __restrict__ bsum, int B) {
    __shared__ int sm[256];
    int t = threadIdx.x;
    int v = (t < B) ? bsum[t] : 0;
    sm[t] = v;
    __syncthreads();
    for (int of = 1; of < 256; of <<= 1) {
        int u = (t >= of) ? sm[t - of] : 0;
        __syncthreads();
        sm[t] += u;
        __syncthreads();
    }
    if (t < B) bsum_ex[t] = sm[t] - v;
}

__global__ void scan_final(const int* __restrict__ count, const int* __restrict__ bsum_ex,
                           int* __restrict__ offsets, int n) {
    __shared__ int sm[256];
    int t = threadIdx.x, b = blockIdx.x;
    int base = b * 1024 + t * 4;
    int c[4];
#pragma unroll
    for (int j = 0; j < 4; ++j) c[j] = (base + j < n) ? count[base + j] : 0;
    int tsum = c[0] + c[1] + c[2] + c[3];
    sm[t] = tsum;
    __syncthreads();
    for (int of = 1; of < 256; of <<= 1) {
        int u = (t >= of) ? sm[t - of] : 0;
        __syncthreads();
        sm[t] += u;
        __syncthreads();
    }
    int o = bsum_ex[b] + sm[t] - tsum;
#pragma unroll
    for (int j = 0; j < 4; ++j) {
        if (base + j < n) offsets[base + j] = o;
        o += c[j];
    }
}

__global__ void scatter_kernel(const void* __restrict__ ei, const int* __restrict__ flag,
                               const int* __restrict__ offsets, int* __restrict__ cursor,
                               int* __restrict__ col, int E) {
    int e = blockIdx.x * blockDim.x + threadIdx.x;
    if (e >= E) return;
    int is64 = *flag;
    int src = load_idx(ei, e, is64);
    int dst = load_idx(ei, (long long)E + e, is64);
    int pos = offsets[dst] + atomicAdd(&cursor[dst], 1);
    col[pos] = src;
}

// ---------------- f32 GEMM: Y = X @ W, output in PAIRED layout ----------------
// Paired layout: for node r, pair p (0..63) holds (col p, col p+64) at floats
// [r*128 + 2p, r*128 + 2p + 1]. Gather in fused_agg reads one dwordx2 per lane.
__launch_bounds__(256, 2)
__global__ void gemm_nn_128(const float* __restrict__ X, const float* __restrict__ W,
                            float* __restrict__ Yp, int n) {
    __shared__ float Xt[64][68];   // [k][r]
    __shared__ float Wl[64][128];  // [k][c]
    const int t = threadIdx.x;
    const int r0 = blockIdx.x * 64;
    const int rb = (t >> 4) * 4;
    const int cb = (t & 15) * 4;
    float acc[4][8] = {};
    for (int ph = 0; ph < 2; ++ph) {
#pragma unroll
        for (int it = 0; it < 4; ++it) {
            int idx = t + it * 256;
            int r = idx >> 4, kq = idx & 15;
            float4 xv = make_float4(0.f, 0.f, 0.f, 0.f);
            if (r0 + r < n)
                xv = *reinterpret_cast<const float4*>(X + (size_t)(r0 + r) * D + ph * 64 + kq * 4);
            Xt[kq * 4 + 0][r] = xv.x;
            Xt[kq * 4 + 1][r] = xv.y;
            Xt[kq * 4 + 2][r] = xv.z;
            Xt[kq * 4 + 3][r] = xv.w;
        }
#pragma unroll
        for (int it = 0; it < 8; ++it) {
            int idx = t + it * 256;
            int k = idx >> 5, c4 = idx & 31;
            *reinterpret_cast<float4*>(&Wl[k][c4 * 4]) =
                *reinterpret_cast<const float4*>(W + (size_t)(ph * 64 + k) * D + c4 * 4);
        }
        __syncthreads();
#pragma unroll 4
        for (int k = 0; k < 64; ++k) {
            float4 a = *reinterpret_cast<const float4*>(&Xt[k][rb]);
            float4 b0 = *reinterpret_cast<const float4*>(&Wl[k][cb]);
            float4 b1 = *reinterpret_cast<const float4*>(&Wl[k][cb + 64]);
            float av[4] = {a.x, a.y, a.z, a.w};
            float bv[8] = {b0.x, b0.y, b0.z, b0.w, b1.x, b1.y, b1.z, b1.w};
#pragma unroll
            for (int i = 0; i < 4; ++i)
#pragma unroll
                for (int j = 0; j < 8; ++j) acc[i][j] = fmaf(av[i], bv[j], acc[i][j]);
        }
        __syncthreads();
    }
#pragma unroll
    for (int i = 0; i < 4; ++i) {
        int row = r0 + rb + i;
        if (row < n) {
            // pair p = cb+j -> (acc[i][j], acc[i][j+4]) at float offset 2*(cb+j)
            float4 o0 = make_float4(acc[i][0], acc[i][4], acc[i][1], acc[i][5]);
            float4 o1 = make_float4(acc[i][2], acc[i][6], acc[i][3], acc[i][7]);
            *reinterpret_cast<float4*>(Yp + (size_t)row * D + 2 * cb) = o0;
            *reinterpret_cast<float4*>(Yp + (size_t)row * D + 2 * cb + 4) = o1;
        }
    }
}

// ---------------- attention scores from paired xp ----------------
template <int H>
__launch_bounds__(256)
__global__ void score_kernel(const float* __restrict__ xp2, const float* __restrict__ a_src,
                             const float* __restrict__ a_dst, float* __restrict__ s_src,
                             float* __restrict__ s_dst, int n) {
    int wid = (blockIdx.x * 256 + threadIdx.x) >> 6;
    int lane = threadIdx.x & 63;
    if (wid >= n) return;
    float2 xv = reinterpret_cast<const float2*>(xp2 + (size_t)wid * D)[lane];
    float x0 = xv.x, x1 = xv.y;  // channels lane, lane+64
    float ps0 = x0 * a_src[lane], ps1 = x1 * a_src[lane + 64];
    float pd0 = x0 * a_dst[lane], pd1 = x1 * a_dst[lane + 64];
    if (H == 4) {
        for (int m = 16; m >= 1; m >>= 1) {
            ps0 += __shfl_xor(ps0, m);
            ps1 += __shfl_xor(ps1, m);
            pd0 += __shfl_xor(pd0, m);
            pd1 += __shfl_xor(pd1, m);
        }
        if (lane == 0) {
            s_src[wid * 4 + 0] = ps0; s_src[wid * 4 + 2] = ps1;
            s_dst[wid * 4 + 0] = pd0; s_dst[wid * 4 + 2] = pd1;
        }
        if (lane == 32) {
            s_src[wid * 4 + 1] = ps0; s_src[wid * 4 + 3] = ps1;
            s_dst[wid * 4 + 1] = pd0; s_dst[wid * 4 + 3] = pd1;
        }
    } else {
        float ps = ps0 + ps1, pd = pd0 + pd1;
        for (int m = 32; m >= 1; m >>= 1) {
            ps += __shfl_xor(ps, m);
            pd += __shfl_xor(pd, m);
        }
        if (lane == 0) { s_src[wid] = ps; s_dst[wid] = pd; }
    }
}

// ---------------- fused online-softmax + aggregation, wave per node ----------------
// One pass over edges: running (m, l, acc) with rescale on new max. Unroll x4
// for memory-level parallelism (8 row-gathers in flight per wave).
template <int H, bool DO_ELU>
__launch_bounds__(256)
__global__ void fused_agg(const int* __restrict__ col, const int* __restrict__ offsets,
                          const int* __restrict__ deg_arr, const float* __restrict__ xp2,
                          const float* __restrict__ s_src, const float* __restrict__ s_dst,
                          const float* __restrict__ bias, float* __restrict__ out, int n) {
    int wid = (blockIdx.x * 256 + threadIdx.x) >> 6;
    int lane = threadIdx.x & 63;
    if (wid >= n) return;
    const int off = offsets[wid], deg = deg_arr[wid];
    const bool hi = (lane >= 32);
    float sd0, sd1;
    if (H == 4) {
        float4 sdv = *reinterpret_cast<const float4*>(s_dst + (size_t)wid * 4);
        sd0 = hi ? sdv.y : sdv.x;   // head of channel `lane`
        sd1 = hi ? sdv.w : sdv.z;   // head of channel `lane+64`
    } else {
        sd0 = sd1 = s_dst[wid];
    }
    float m0, m1, l0 = 1.f, l1 = 1.f, acc0, acc1;
    {   // self loop (weight exp(0)=1 at running max = own score)
        float ssA, ssB;
        if (H == 4) {
            float4 q = *reinterpret_cast<const float4*>(s_src + (size_t)wid * 4);
            ssA = hi ? q.y : q.x; ssB = hi ? q.w : q.z;
        } else { ssA = ssB = s_src[wid]; }
        m0 = LRELU(ssA + sd0);
        m1 = LRELU(ssB + sd1);
        float2 xv = reinterpret_cast<const float2*>(xp2 + (size_t)wid * D)[lane];
        acc0 = xv.x; acc1 = xv.y;
    }

#define EDGE_UPD(SSA, SSB, XV)                                              \
    {                                                                       \
        float e0 = LRELU((SSA) + sd0);                                      \
        float e1 = LRELU((SSB) + sd1);                                      \
        if (e0 > m0) { float sc = __expf(m0 - e0); l0 *= sc; acc0 *= sc; m0 = e0; } \
        if (e1 > m1) { float sc = __expf(m1 - e1); l1 *= sc; acc1 *= sc; m1 = e1; } \
        float w0 = __expf(e0 - m0), w1 = __expf(e1 - m1);                   \
        l0 += w0; l1 += w1;                                                 \
        acc0 = fmaf(w0, (XV).x, acc0);                                      \
        acc1 = fmaf(w1, (XV).y, acc1);                                      \
    }

    int i = 0;
    for (; i + 4 <= deg; i += 4) {
        int s0 = col[off + i], s1 = col[off + i + 1];
        int s2 = col[off + i + 2], s3 = col[off + i + 3];
        float A0, B0, A1, B1, A2, B2, A3, B3;
        if (H == 4) {
            float4 q0 = *reinterpret_cast<const float4*>(s_src + (size_t)s0 * 4);
            float4 q1 = *reinterpret_cast<const float4*>(s_src + (size_t)s1 * 4);
            float4 q2 = *reinterpret_cast<const float4*>(s_src + (size_t)s2 * 4);
            float4 q3 = *reinterpret_cast<const float4*>(s_src + (size_t)s3 * 4);
            A0 = hi ? q0.y : q0.x; B0 = hi ? q0.w : q0.z;
            A1 = hi ? q1.y : q1.x; B1 = hi ? q1.w : q1.z;
            A2 = hi ? q2.y : q2.x; B2 = hi ? q2.w : q2.z;
            A3 = hi ? q3.y : q3.x; B3 = hi ? q3.w : q3.z;
        } else {
            A0 = B0 = s_src[s0]; A1 = B1 = s_src[s1];
            A2 = B2 = s_src[s2]; A3 = B3 = s_src[s3];
        }
        float2 x0 = reinterpret_cast<const float2*>(xp2 + (size_t)s0 * D)[lane];
        float2 x1 = reinterpret_cast<const float2*>(xp2 + (size_t)s1 * D)[lane];
        float2 x2 = reinterpret_cast<const float2*>(xp2 + (size_t)s2 * D)[lane];
        float2 x3 = reinterpret_cast<const float2*>(xp2 + (size_t)s3 * D)[lane];
        EDGE_UPD(A0, B0, x0);
        EDGE_UPD(A1, B1, x1);
        EDGE_UPD(A2, B2, x2);
        EDGE_UPD(A3, B3, x3);
    }
    for (; i < deg; ++i) {
        int s = col[off + i];
        float A, B;
        if (H == 4) {
            float4 q = *reinterpret_cast<const float4*>(s_src + (size_t)s * 4);
            A = hi ? q.y : q.x; B = hi ? q.w : q.z;
        } else { A = B = s_src[s]; }
        float2 xv = reinterpret_cast<const float2*>(xp2 + (size_t)s * D)[lane];
        EDGE_UPD(A, B, xv);
    }
#undef EDGE_UPD

    float rd0 = 1.f / (l0 + 1e-16f);
    float rd1 = 1.f / (l1 + 1e-16f);
    float v0 = acc0 * rd0 + bias[lane];
    float v1 = acc1 * rd1 + bias[lane + 64];
    if (DO_ELU) {
        v0 = v0 > 0.f ? v0 : expm1f(v0);
        v1 = v1 > 0.f ? v1 : expm1f(v1);
    }
    out[(size_t)wid * D + lane] = v0;
    out[(size_t)wid * D + lane + 64] = v1;
}

// ---------------- launch ----------------
extern "C" void kernel_launch(void* const* d_in, const int* in_sizes, int n_in,
                              void* d_out, int out_size, void* d_ws, size_t ws_size,
                              hipStream_t stream) {
    (void)n_in; (void)out_size; (void)ws_size;
    const float* x   = (const float*)d_in[0];
    const void*  ei  = d_in[1];
    const float* W1  = (const float*)d_in[2];
    const float* a1s = (const float*)d_in[3];
    const float* a1d = (const float*)d_in[4];
    const float* b1  = (const float*)d_in[5];
    const float* W2  = (const float*)d_in[6];
    const float* a2s = (const float*)d_in[7];
    const float* a2d = (const float*)d_in[8];
    const float* b2  = (const float*)d_in[9];
    const int N = in_sizes[0] / D;  // 100000
    const int E = in_sizes[1] / 2;  // 1600000
    float* out = (float*)d_out;

    char* p = (char*)d_ws;
    auto alloc = [&](size_t bytes) {
        char* q = p;
        p += (bytes + 255) & ~(size_t)255;
        return q;
    };
    float* xp      = (float*)alloc((size_t)N * D * 4);   // paired layout
    float* ssrc    = (float*)alloc((size_t)N * 4 * 4);
    float* sdst    = (float*)alloc((size_t)N * 4 * 4);
    int*   count   = (int*)alloc((size_t)N * 4);
    int*   cursor  = (int*)alloc((size_t)N * 4);
    int*   offsets = (int*)alloc((size_t)N * 4);
    int*   bsum    = (int*)alloc(256 * 4);
    int*   bsumex  = (int*)alloc(256 * 4);
    int*   flag    = (int*)alloc(256);
    int*   col     = (int*)alloc((size_t)E * 4);

    hipMemsetAsync(count, 0, (size_t)N * 4, stream);
    hipMemsetAsync(cursor, 0, (size_t)N * 4, stream);

    detect_i64<<<1, 64, 0, stream>>>((const unsigned int*)ei, flag);
    int eg = (E + 255) / 256;
    hist_kernel<<<eg, 256, 0, stream>>>(ei, flag, count, E);
    int B = (N + 1023) / 1024;
    reduce_1024<<<B, 256, 0, stream>>>(count, bsum, N);
    scan_partials<<<1, 256, 0, stream>>>(bsumex, bsum, B);
    scan_final<<<B, 256, 0, stream>>>(count, bsumex, offsets, N);
    scatter_kernel<<<eg, 256, 0, stream>>>(ei, flag, offsets, cursor, col, E);

    int gemmG = (N + 63) / 64;
    int nodeG = (N + 3) / 4;

    // ----- layer 1 (H=4, ELU) -----
    gemm_nn_128<<<gemmG, 256, 0, stream>>>(x, W1, xp, N);
    score_kernel<4><<<nodeG, 256, 0, stream>>>(xp, a1s, a1d, ssrc, sdst, N);
    fused_agg<4, true><<<nodeG, 256, 0, stream>>>(col, offsets, count, xp, ssrc, sdst, b1, out, N);

    // ----- layer 2 (H=1, no activation) -----
    gemm_nn_128<<<gemmG, 256, 0, stream>>>(out, W2, xp, N);
    score_kernel<1><<<nodeG, 256, 0, stream>>>(xp, a2s, a2d, ssrc, sdst, N);
    fused_agg<1, false><<<nodeG, 256, 0, stream>>>(col, offsets, count, xp, ssrc, sdst, b2, out, N);
}